// Round 19
// baseline (382.588 us; speedup 1.0000x reference)
//
#include <hip/hip_runtime.h>

// GraphAttentionLayer: B=8, N=2048, F=256, H=8, D=32. f32 in/out, adj int32.
// R19: R18's attn phases A/B untouched (the L2-stable equilibrium: 512x512thr,
// b=id&7, q-tile 32, fused ls+unnormPV / out2). NEW: phase C fuses oproj+LN
// into k_attn (ao lives in LDS, k_oproj deleted); adj-pack folded into k_qkv
// (overlaps HBM-bound pack with compute-bound QKV). 3 launches total.

typedef __attribute__((ext_vector_type(8))) short short8;
typedef __attribute__((ext_vector_type(4))) float f32x4;
typedef __attribute__((ext_vector_type(4))) unsigned short us4;
typedef unsigned short u16;
typedef unsigned int u32;

#define SC2 0.25503486127240555f   // log2(e)/sqrt(32)

__device__ __forceinline__ u16 cvt(float f) {  // RNE via HW cvt
  __bf16 h = (__bf16)f;
  union { __bf16 h; u16 u; } v; v.h = h; return v.u;
}

// ---------------- prep: W transpose f32 -> bf16 (x4) ----------------
__global__ __launch_bounds__(256) void k_prep(
    const float* __restrict__ w0, const float* __restrict__ w1,
    const float* __restrict__ w2, const float* __restrict__ w3,
    u16* __restrict__ o0, u16* __restrict__ o1,
    u16* __restrict__ o2, u16* __restrict__ o3) {
  int bid = blockIdx.x;
  int z = bid >> 6, rem = bid & 63;
  const float* in; u16* out;
  if (z == 0) { in = w0; out = o0; }
  else if (z == 1) { in = w1; out = o1; }
  else if (z == 2) { in = w2; out = o2; }
  else { in = w3; out = o3; }
  __shared__ u16 t[32][33];
  int tx = threadIdx.x & 31, ty = threadIdx.x >> 5;
  int x0 = (rem & 7) * 32, y0 = (rem >> 3) * 32;
  for (int j = 0; j < 32; j += 8)
    t[ty + j][tx] = cvt(in[(y0 + ty + j) * 256 + x0 + tx]);
  __syncthreads();
  for (int j = 0; j < 32; j += 8)
    out[(x0 + ty + j) * 256 + y0 + tx] = t[tx][ty + j];
}

// -------- QKV projection (blocks 0..3071) + adj pack (3072..5119) --------
__global__ __launch_bounds__(256) void k_qkvpack(
    const float* __restrict__ x, const u16* __restrict__ wt,
    const float* __restrict__ bq, const float* __restrict__ bk,
    const float* __restrict__ bv,
    u16* __restrict__ qw, u16* __restrict__ kw, u16* __restrict__ vt,
    const int* __restrict__ adj, u32* __restrict__ packed) {
  int bid = blockIdx.x;
  if (bid >= 3072) {  // ---- adj -> bit pack, grid-strided ----
    int lane = threadIdx.x & 63;
#pragma unroll 4
    for (int it = 0; it < 64; it++) {
      unsigned int i = ((bid - 3072) * 64u + it) * 256u + threadIdx.x;
      unsigned long long m = __ballot(adj[i] != 0);
      if (lane == 0)       packed[i >> 5] = (u32)m;
      else if (lane == 32) packed[i >> 5] = (u32)(m >> 32);
    }
    return;
  }
  int bx = bid % 12, by = bid / 12;
  int l = threadIdx.x & 63, w = threadIdx.x >> 6;
  int lr = l & 15, lg = l >> 4;
  int row0 = by * 64 + w * 16;
  int c0 = bx * 64;
  f32x4 acc[4] = {};
  const float* xr = x + (size_t)(row0 + lr) * 256 + lg * 8;
  const u16* wr = wt + (c0 + lr) * 256 + lg * 8;
  for (int k0 = 0; k0 < 256; k0 += 32) {
    f32x4 f0 = *(const f32x4*)(xr + k0);
    f32x4 f1 = *(const f32x4*)(xr + k0 + 4);
    short8 a;
    a[0] = (short)cvt(f0[0]); a[1] = (short)cvt(f0[1]);
    a[2] = (short)cvt(f0[2]); a[3] = (short)cvt(f0[3]);
    a[4] = (short)cvt(f1[0]); a[5] = (short)cvt(f1[1]);
    a[6] = (short)cvt(f1[2]); a[7] = (short)cvt(f1[3]);
#pragma unroll
    for (int ct = 0; ct < 4; ct++) {
      short8 bb = *(const short8*)(wr + ct * 16 * 256 + k0);
      acc[ct] = __builtin_amdgcn_mfma_f32_16x16x32_bf16(a, bb, acc[ct], 0, 0, 0);
    }
  }
  int mtx = bx >> 2;  // 0=q 1=k 2=v
  const float* bias = (mtx == 0) ? bq : ((mtx == 1) ? bk : bv);
  int b = row0 >> 11, nbase = row0 & 2047;
#pragma unroll
  for (int ct = 0; ct < 4; ct++) {
    int cc = (c0 + ct * 16 + lr) & 255;
    int h = cc >> 5, d = cc & 31;
    float bs = bias[cc];
    if (mtx < 2) {
      u16* dst = (mtx == 0) ? qw : kw;
      float sc = (mtx == 0) ? SC2 : 1.0f;
#pragma unroll
      for (int rr = 0; rr < 4; rr++) {
        int n = nbase + lg * 4 + rr;
        dst[((b * 8 + h) * 2048 + n) * 32 + d] = cvt((acc[ct][rr] + bs) * sc);
      }
    } else {
      us4 pk;
#pragma unroll
      for (int rr = 0; rr < 4; rr++) pk[rr] = cvt(acc[ct][rr] + bs);
      *(us4*)(vt + (size_t)((b * 8 + h) * 32 + d) * 2048 + nbase + lg * 4) = pk;
    }
  }
}

// ---- attention + oproj + LN: A = ls+PV -> aoL, B = out2, C = oproj+LN ----
// 1D grid 512: b = id & 7 (pins batch to XCD), q0 = (id >> 3) * 32.
// Block 512thr = 8 waves. Phase A: wave = head (ao -> LDS). Phase B: wave =
// (q-half, k-quarter), out2. Phase C: wave = (row-half, col-group), oproj+LN.
__global__ __launch_bounds__(512) void k_attn(
    const u16* __restrict__ qw, const u16* __restrict__ kw,
    const u16* __restrict__ vt, const u32* __restrict__ packed,
    const u16* __restrict__ wto, const float* __restrict__ bo,
    const float* __restrict__ gamma, const float* __restrict__ beta,
    float* __restrict__ out, float* __restrict__ out2) {
  __shared__ __align__(16) u16 P[8][2048];   // [head][32r x 64c swizzled]
  __shared__ __align__(16) u16 aoL[32 * 264]; // 32 rows x 256 (+8 pad)
  __shared__ float lsbuf[8][32];
  __shared__ float lnb[32][4][2];            // [row][col-group][sum,sq]
  int l = threadIdx.x & 63, wv = threadIdx.x >> 6;
  int lr = l & 15, lg = l >> 4;
  int b = blockIdx.x & 7, q0 = (blockIdx.x >> 3) * 32;
  const u32* pkb = packed + (size_t)(b * 2048 + q0) * 64;

  // ---- phase A: wave = head wv; e' = exp2(s); ls + unnormalized PV ----
  {
    int h = wv;
    const u16* qb = qw + (size_t)((b * 8 + h) * 2048 + q0) * 32;
    const u16* kb = kw + (size_t)((b * 8 + h) * 2048) * 32;
    const u16* vb = vt + (size_t)((b * 8 + h) * 32) * 2048;
    short8 qf0 = *(const short8*)(qb + lr * 32 + lg * 8);
    short8 qf1 = *(const short8*)(qb + (16 + lr) * 32 + lg * 8);
    u16* Pt = &P[h][0];
    float ls0 = 0.f, ls1 = 0.f;
    f32x4 acc[2][2] = {};
#pragma unroll 2
    for (int ch = 0; ch < 32; ch++) {
      uint2 m0 = *(const uint2*)(pkb + lr * 64 + ch * 2);
      uint2 m1 = *(const uint2*)(pkb + (16 + lr) * 64 + ch * 2);
#pragma unroll
      for (int j = 0; j < 4; j++) {
        short8 kf = *(const short8*)(kb + (size_t)(ch * 64 + j * 16 + lr) * 32 + lg * 8);
        f32x4 z = {};
        f32x4 s0 = __builtin_amdgcn_mfma_f32_16x16x32_bf16(kf, qf0, z, 0, 0, 0);
        f32x4 s1 = __builtin_amdgcn_mfma_f32_16x16x32_bf16(kf, qf1, z, 0, 0, 0);
        u32 w0 = ((j & 2) ? m0.y : m0.x) >> ((j & 1) * 16 + lg * 4);
        u32 w1 = ((j & 2) ? m1.y : m1.x) >> ((j & 1) * 16 + lg * 4);
        us4 p0, p1;
#pragma unroll
        for (int rr = 0; rr < 4; rr++) {
          float e0 = __builtin_exp2f(s0[rr]);
          float e1 = __builtin_exp2f(s1[rr]);
          float em0 = ((w0 >> rr) & 1u) ? e0 : 0.0f;
          float em1 = ((w1 >> rr) & 1u) ? e1 : 0.0f;
          ls0 += em0; ls1 += em1;
          p0[rr] = cvt(em0); p1[rr] = cvt(em1);
        }
        int slot = 2 * j + (lg >> 1), offs = (lg & 1) * 4;
        *(us4*)(Pt + lr * 64 + ((slot ^ (lr & 7)) << 3) + offs) = p0;
        *(us4*)(Pt + (16 + lr) * 64 + ((slot ^ (lr & 7)) << 3) + offs) = p1;
      }
      // PV (unnormalized) from own wave's P tile
#pragma unroll
      for (int k2 = 0; k2 < 2; k2++) {
        short8 pa0 = *(const short8*)(Pt + lr * 64 +
                        (((k2 * 4 + lg) ^ (lr & 7)) << 3));
        short8 pa1 = *(const short8*)(Pt + (16 + lr) * 64 +
                        (((k2 * 4 + lg) ^ (lr & 7)) << 3));
#pragma unroll
        for (int dt = 0; dt < 2; dt++) {
          short8 vf = *(const short8*)(vb + (size_t)(dt * 16 + lr) * 2048 +
                                       ch * 64 + k2 * 32 + lg * 8);
          acc[0][dt] = __builtin_amdgcn_mfma_f32_16x16x32_bf16(pa0, vf, acc[0][dt], 0, 0, 0);
          acc[1][dt] = __builtin_amdgcn_mfma_f32_16x16x32_bf16(pa1, vf, acc[1][dt], 0, 0, 0);
        }
      }
    }
    ls0 += __shfl_xor(ls0, 16); ls0 += __shfl_xor(ls0, 32);
    ls1 += __shfl_xor(ls1, 16); ls1 += __shfl_xor(ls1, 32);
    ls0 = fmaxf(ls0, 1e-30f); ls1 = fmaxf(ls1, 1e-30f);
    if (l < 16) { lsbuf[h][lr] = ls0; lsbuf[h][16 + lr] = ls1; }
    float r0 = 1.0f / ls0, r1 = 1.0f / ls1;
#pragma unroll
    for (int qs = 0; qs < 2; qs++)
#pragma unroll
      for (int rr = 0; rr < 4; rr++) {
        float rq = __shfl(qs == 0 ? r0 : r1, lg * 4 + rr);
#pragma unroll
        for (int dt = 0; dt < 2; dt++) {
          aoL[(qs * 16 + lg * 4 + rr) * 264 + h * 32 + dt * 16 + lr] =
              cvt(acc[qs][dt][rr] * rq);
        }
      }
  }
  __syncthreads();

  // ---- phase B: out2 = mask * sum_h exp2(s)*rls8_h  (rls8 = 0.125/ls) ----
  {
    int qh = (wv >> 2) * 16;   // q-half
    int c0 = (wv & 3) * 8;     // chunk quarter
    short8 qfh[8];
    float rls8[8];
#pragma unroll
    for (int hh = 0; hh < 8; hh++) {
      qfh[hh] = *(const short8*)(qw +
          (size_t)((b * 8 + hh) * 2048 + q0 + qh + lr) * 32 + lg * 8);
      rls8[hh] = 0.125f / lsbuf[hh][qh + lr];
    }
    const u32* pkb2 = packed + (size_t)(b * 2048 + q0 + qh) * 64;
#pragma unroll 2
    for (int ch = c0; ch < c0 + 8; ch++) {
      uint2 mw = *(const uint2*)(pkb2 + lr * 64 + ch * 2);
#pragma unroll
      for (int j = 0; j < 4; j++) {
        f32x4 macc = {};
#pragma unroll
        for (int hh = 0; hh < 8; hh++) {
          const u16* kbh = kw + (size_t)((b * 8 + hh) * 2048) * 32;
          short8 kf = *(const short8*)(kbh +
              (size_t)(ch * 64 + j * 16 + lr) * 32 + lg * 8);
          f32x4 z = {};
          f32x4 s = __builtin_amdgcn_mfma_f32_16x16x32_bf16(kf, qfh[hh], z, 0, 0, 0);
#pragma unroll
          for (int rr = 0; rr < 4; rr++)
            macc[rr] = fmaf(__builtin_exp2f(s[rr]), rls8[hh], macc[rr]);
        }
        u32 wj = ((j & 2) ? mw.y : mw.x) >> ((j & 1) * 16 + lg * 4);
        f32x4 o;
#pragma unroll
        for (int rr = 0; rr < 4; rr++)
          o[rr] = ((wj >> rr) & 1u) ? macc[rr] : 0.0f;
        *(f32x4*)(out2 + (size_t)(b * 2048 + q0 + qh + lr) * 2048 +
                  ch * 64 + j * 16 + lg * 4) = o;
      }
    }
  }

  // ---- phase C: oproj + LN for this block's 32 rows ----
  {
    int rh = wv & 1, cg = wv >> 1;  // row-half (16 rows), col-group (64 cols)
    f32x4 acc[4] = {};
    const u16* wr = wto + (cg * 64 + lr) * 256 + lg * 8;
    for (int k0 = 0; k0 < 256; k0 += 32) {
      short8 a = *(const short8*)(&aoL[(rh * 16 + lr) * 264 + k0 + lg * 8]);
#pragma unroll
      for (int ct = 0; ct < 4; ct++) {
        short8 bb = *(const short8*)(wr + ct * 16 * 256 + k0);
        acc[ct] = __builtin_amdgcn_mfma_f32_16x16x32_bf16(a, bb, acc[ct], 0, 0, 0);
      }
    }
    float sum[4] = {0, 0, 0, 0}, sq[4] = {0, 0, 0, 0};
#pragma unroll
    for (int ct = 0; ct < 4; ct++) {
      float bs = bo[cg * 64 + ct * 16 + lr];
#pragma unroll
      for (int rr = 0; rr < 4; rr++) {
        float v = acc[ct][rr] + bs;
        acc[ct][rr] = v;
        sum[rr] += v; sq[rr] += v * v;
      }
    }
#pragma unroll
    for (int rr = 0; rr < 4; rr++) {
      float s = sum[rr], q = sq[rr];
      s += __shfl_xor(s, 1); s += __shfl_xor(s, 2);
      s += __shfl_xor(s, 4); s += __shfl_xor(s, 8);
      q += __shfl_xor(q, 1); q += __shfl_xor(q, 2);
      q += __shfl_xor(q, 4); q += __shfl_xor(q, 8);
      sum[rr] = s; sq[rr] = q;
    }
    if ((l & 15) == 0) {
#pragma unroll
      for (int rr = 0; rr < 4; rr++) {
        int row = rh * 16 + lg * 4 + rr;
        lnb[row][cg][0] = sum[rr];
        lnb[row][cg][1] = sq[rr];
      }
    }
    __syncthreads();
#pragma unroll
    for (int rr = 0; rr < 4; rr++) {
      int row = rh * 16 + lg * 4 + rr;
      float S = lnb[row][0][0] + lnb[row][1][0] + lnb[row][2][0] + lnb[row][3][0];
      float Q = lnb[row][0][1] + lnb[row][1][1] + lnb[row][2][1] + lnb[row][3][1];
      float mu = S * (1.0f / 256.0f);
      float var = fmaxf(Q * (1.0f / 256.0f) - mu * mu, 0.0f);
      float rs = rsqrtf(var + 1e-5f);
      size_t obase = (size_t)(b * 2048 + q0 + row) * 256 + cg * 64;
#pragma unroll
      for (int ct = 0; ct < 4; ct++) {
        float g = gamma[cg * 64 + ct * 16 + lr];
        float be = beta[cg * 64 + ct * 16 + lr];
        out[obase + ct * 16 + lr] = (acc[ct][rr] - mu) * rs * g + be;
      }
    }
  }
}

extern "C" void kernel_launch(void* const* d_in, const int* in_sizes, int n_in,
                              void* d_out, int out_size, void* d_ws, size_t ws_size,
                              hipStream_t stream) {
  const float* x    = (const float*)d_in[0];
  const int*   adj  = (const int*)d_in[1];
  const float* Wq   = (const float*)d_in[2];
  const float* bq   = (const float*)d_in[3];
  const float* Wk   = (const float*)d_in[4];
  const float* bk   = (const float*)d_in[5];
  const float* Wv   = (const float*)d_in[6];
  const float* bv   = (const float*)d_in[7];
  const float* Wo   = (const float*)d_in[8];
  const float* bo   = (const float*)d_in[9];
  const float* gamma= (const float*)d_in[10];
  const float* beta = (const float*)d_in[11];

  char* ws = (char*)d_ws;
  u16* wtq = (u16*)(ws + 0);
  u16* wtk = (u16*)(ws + 131072);
  u16* wtv = (u16*)(ws + 262144);
  u16* wto = (u16*)(ws + 393216);
  u16* qw  = (u16*)(ws + 524288);
  u16* kw  = (u16*)(ws + 8912896);
  u16* vt  = (u16*)(ws + 17301504);
  u32* pk  = (u32*)(ws + 34078720);

  float* out  = (float*)d_out;
  float* out2 = out + (size_t)8 * 2048 * 256;

  k_prep<<<dim3(256), dim3(256), 0, stream>>>(Wq, Wk, Wv, Wo,
                                              wtq, wtk, wtv, wto);
  k_qkvpack<<<dim3(5120), dim3(256), 0, stream>>>(x, wtq, bq, bk, bv,
                                                  qw, kw, vt, adj, pk);
  k_attn<<<dim3(512), dim3(512), 0, stream>>>(qw, kw, vt, pk, wto, bo,
                                              gamma, beta, out, out2);
}

// Round 20
// 344.245 us; speedup vs baseline: 1.1114x; 1.1114x over previous
//
#include <hip/hip_runtime.h>

// GraphAttentionLayer: B=8, N=2048, F=256, H=8, D=32. f32 in/out, adj int32.
// R20: R18 exactly (the proven L2-stable equilibrium: 512x512thr, b=id&7,
// q-tile 32, fused A=ls+unnormPV / B=out2, unroll-2, separate prep/qkv/oproj)
// + T5: s_setprio(1) around MFMA clusters (catalog: +4-7% attn, m191).

typedef __attribute__((ext_vector_type(8))) short short8;
typedef __attribute__((ext_vector_type(4))) float f32x4;
typedef __attribute__((ext_vector_type(4))) unsigned short us4;
typedef unsigned short u16;
typedef unsigned int u32;

#define SC2 0.25503486127240555f   // log2(e)/sqrt(32)

__device__ __forceinline__ u16 cvt(float f) {  // RNE via HW cvt
  __bf16 h = (__bf16)f;
  union { __bf16 h; u16 u; } v; v.h = h; return v.u;
}

// ------------- prep: W transpose (blocks 0..255) + adj pack (256..2303) ----
__global__ __launch_bounds__(256) void k_prep(
    const int* __restrict__ adj, u32* __restrict__ packed,
    const float* __restrict__ w0, const float* __restrict__ w1,
    const float* __restrict__ w2, const float* __restrict__ w3,
    u16* __restrict__ o0, u16* __restrict__ o1,
    u16* __restrict__ o2, u16* __restrict__ o3) {
  int bid = blockIdx.x;
  if (bid < 256) {
    int z = bid >> 6, rem = bid & 63;
    const float* in; u16* out;
    if (z == 0) { in = w0; out = o0; }
    else if (z == 1) { in = w1; out = o1; }
    else if (z == 2) { in = w2; out = o2; }
    else { in = w3; out = o3; }
    __shared__ u16 t[32][33];
    int tx = threadIdx.x & 31, ty = threadIdx.x >> 5;
    int x0 = (rem & 7) * 32, y0 = (rem >> 3) * 32;
    for (int j = 0; j < 32; j += 8)
      t[ty + j][tx] = cvt(in[(y0 + ty + j) * 256 + x0 + tx]);
    __syncthreads();
    for (int j = 0; j < 32; j += 8)
      out[(x0 + ty + j) * 256 + y0 + tx] = t[tx][ty + j];
  } else {
    int lane = threadIdx.x & 63;
#pragma unroll 4
    for (int it = 0; it < 64; it++) {
      unsigned int i = ((bid - 256) * 64u + it) * 256u + threadIdx.x;
      unsigned long long m = __ballot(adj[i] != 0);
      if (lane == 0)       packed[i >> 5] = (u32)m;
      else if (lane == 32) packed[i >> 5] = (u32)(m >> 32);
    }
  }
}

// ---------------- QKV projection (Q pre-scaled by SC2) ----------------
__global__ __launch_bounds__(256) void k_qkv(
    const float* __restrict__ x, const u16* __restrict__ wt,
    const float* __restrict__ bq, const float* __restrict__ bk,
    const float* __restrict__ bv,
    u16* __restrict__ qw, u16* __restrict__ kw, u16* __restrict__ vt) {
  int l = threadIdx.x & 63, w = threadIdx.x >> 6;
  int lr = l & 15, lg = l >> 4;
  int row0 = blockIdx.y * 64 + w * 16;
  int c0 = blockIdx.x * 64;
  f32x4 acc[4] = {};
  const float* xr = x + (size_t)(row0 + lr) * 256 + lg * 8;
  const u16* wr = wt + (c0 + lr) * 256 + lg * 8;
  for (int k0 = 0; k0 < 256; k0 += 32) {
    f32x4 f0 = *(const f32x4*)(xr + k0);
    f32x4 f1 = *(const f32x4*)(xr + k0 + 4);
    short8 a;
    a[0] = (short)cvt(f0[0]); a[1] = (short)cvt(f0[1]);
    a[2] = (short)cvt(f0[2]); a[3] = (short)cvt(f0[3]);
    a[4] = (short)cvt(f1[0]); a[5] = (short)cvt(f1[1]);
    a[6] = (short)cvt(f1[2]); a[7] = (short)cvt(f1[3]);
#pragma unroll
    for (int ct = 0; ct < 4; ct++) {
      short8 bb = *(const short8*)(wr + ct * 16 * 256 + k0);
      acc[ct] = __builtin_amdgcn_mfma_f32_16x16x32_bf16(a, bb, acc[ct], 0, 0, 0);
    }
  }
  int mtx = blockIdx.x >> 2;  // 0=q 1=k 2=v
  const float* bias = (mtx == 0) ? bq : ((mtx == 1) ? bk : bv);
  int b = row0 >> 11, nbase = row0 & 2047;
#pragma unroll
  for (int ct = 0; ct < 4; ct++) {
    int cc = (c0 + ct * 16 + lr) & 255;
    int h = cc >> 5, d = cc & 31;
    float bs = bias[cc];
    if (mtx < 2) {
      u16* dst = (mtx == 0) ? qw : kw;
      float sc = (mtx == 0) ? SC2 : 1.0f;
#pragma unroll
      for (int rr = 0; rr < 4; rr++) {
        int n = nbase + lg * 4 + rr;
        dst[((b * 8 + h) * 2048 + n) * 32 + d] = cvt((acc[ct][rr] + bs) * sc);
      }
    } else {
      us4 pk;
#pragma unroll
      for (int rr = 0; rr < 4; rr++) pk[rr] = cvt(acc[ct][rr] + bs);
      *(us4*)(vt + (size_t)((b * 8 + h) * 32 + d) * 2048 + nbase + lg * 4) = pk;
    }
  }
}

// ---------------- attention: A = ls+PV (deferred norm), B = out2 ----------
// 1D grid 512: b = id & 7 (pins batch to XCD), q0 = (id >> 3) * 32.
// Block 512thr = 8 waves. Phase A: wave = head. Phase B: wave = (q-half,
// k-quarter), h-loop innermost. T5 setprio around MFMA clusters.
__global__ __launch_bounds__(512) void k_attn(
    const u16* __restrict__ qw, const u16* __restrict__ kw,
    const u16* __restrict__ vt, const u32* __restrict__ packed,
    u16* __restrict__ ao, float* __restrict__ out2) {
  __shared__ __align__(16) u16 P[8][2048];  // [head][32r x 64c swizzled]
  __shared__ float lsbuf[8][32];
  int l = threadIdx.x & 63, wv = threadIdx.x >> 6;
  int lr = l & 15, lg = l >> 4;
  int b = blockIdx.x & 7, q0 = (blockIdx.x >> 3) * 32;
  const u32* pkb = packed + (size_t)(b * 2048 + q0) * 64;

  // ---- phase A: wave = head wv; e' = exp2(s); ls + unnormalized PV ----
  {
    int h = wv;
    const u16* qb = qw + (size_t)((b * 8 + h) * 2048 + q0) * 32;
    const u16* kb = kw + (size_t)((b * 8 + h) * 2048) * 32;
    const u16* vb = vt + (size_t)((b * 8 + h) * 32) * 2048;
    short8 qf0 = *(const short8*)(qb + lr * 32 + lg * 8);
    short8 qf1 = *(const short8*)(qb + (16 + lr) * 32 + lg * 8);
    u16* Pt = &P[h][0];
    float ls0 = 0.f, ls1 = 0.f;
    f32x4 acc[2][2] = {};
#pragma unroll 2
    for (int ch = 0; ch < 32; ch++) {
      uint2 m0 = *(const uint2*)(pkb + lr * 64 + ch * 2);
      uint2 m1 = *(const uint2*)(pkb + (16 + lr) * 64 + ch * 2);
#pragma unroll
      for (int j = 0; j < 4; j++) {
        short8 kf = *(const short8*)(kb + (size_t)(ch * 64 + j * 16 + lr) * 32 + lg * 8);
        f32x4 z = {};
        __builtin_amdgcn_s_setprio(1);
        f32x4 s0 = __builtin_amdgcn_mfma_f32_16x16x32_bf16(kf, qf0, z, 0, 0, 0);
        f32x4 s1 = __builtin_amdgcn_mfma_f32_16x16x32_bf16(kf, qf1, z, 0, 0, 0);
        __builtin_amdgcn_s_setprio(0);
        u32 w0 = ((j & 2) ? m0.y : m0.x) >> ((j & 1) * 16 + lg * 4);
        u32 w1 = ((j & 2) ? m1.y : m1.x) >> ((j & 1) * 16 + lg * 4);
        us4 p0, p1;
#pragma unroll
        for (int rr = 0; rr < 4; rr++) {
          float e0 = __builtin_exp2f(s0[rr]);
          float e1 = __builtin_exp2f(s1[rr]);
          float em0 = ((w0 >> rr) & 1u) ? e0 : 0.0f;
          float em1 = ((w1 >> rr) & 1u) ? e1 : 0.0f;
          ls0 += em0; ls1 += em1;
          p0[rr] = cvt(em0); p1[rr] = cvt(em1);
        }
        int slot = 2 * j + (lg >> 1), offs = (lg & 1) * 4;
        *(us4*)(Pt + lr * 64 + ((slot ^ (lr & 7)) << 3) + offs) = p0;
        *(us4*)(Pt + (16 + lr) * 64 + ((slot ^ (lr & 7)) << 3) + offs) = p1;
      }
      // PV (unnormalized) from own wave's P tile
#pragma unroll
      for (int k2 = 0; k2 < 2; k2++) {
        short8 pa0 = *(const short8*)(Pt + lr * 64 +
                        (((k2 * 4 + lg) ^ (lr & 7)) << 3));
        short8 pa1 = *(const short8*)(Pt + (16 + lr) * 64 +
                        (((k2 * 4 + lg) ^ (lr & 7)) << 3));
        __builtin_amdgcn_s_setprio(1);
#pragma unroll
        for (int dt = 0; dt < 2; dt++) {
          short8 vf = *(const short8*)(vb + (size_t)(dt * 16 + lr) * 2048 +
                                       ch * 64 + k2 * 32 + lg * 8);
          acc[0][dt] = __builtin_amdgcn_mfma_f32_16x16x32_bf16(pa0, vf, acc[0][dt], 0, 0, 0);
          acc[1][dt] = __builtin_amdgcn_mfma_f32_16x16x32_bf16(pa1, vf, acc[1][dt], 0, 0, 0);
        }
        __builtin_amdgcn_s_setprio(0);
      }
    }
    ls0 += __shfl_xor(ls0, 16); ls0 += __shfl_xor(ls0, 32);
    ls1 += __shfl_xor(ls1, 16); ls1 += __shfl_xor(ls1, 32);
    ls0 = fmaxf(ls0, 1e-30f); ls1 = fmaxf(ls1, 1e-30f);
    if (l < 16) { lsbuf[h][lr] = ls0; lsbuf[h][16 + lr] = ls1; }
    float r0 = 1.0f / ls0, r1 = 1.0f / ls1;
#pragma unroll
    for (int qs = 0; qs < 2; qs++)
#pragma unroll
      for (int rr = 0; rr < 4; rr++) {
        float rq = __shfl(qs == 0 ? r0 : r1, lg * 4 + rr);
#pragma unroll
        for (int dt = 0; dt < 2; dt++) {
          int n = q0 + qs * 16 + lg * 4 + rr;
          ao[(size_t)(b * 2048 + n) * 256 + h * 32 + dt * 16 + lr] =
              cvt(acc[qs][dt][rr] * rq);
        }
      }
  }
  __syncthreads();

  // ---- phase B: out2 = mask * sum_h exp2(s)*rls8_h  (rls8 = 0.125/ls) ----
  {
    int qh = (wv >> 2) * 16;   // q-half
    int c0 = (wv & 3) * 8;     // chunk quarter
    short8 qfh[8];
    float rls8[8];
#pragma unroll
    for (int hh = 0; hh < 8; hh++) {
      qfh[hh] = *(const short8*)(qw +
          (size_t)((b * 8 + hh) * 2048 + q0 + qh + lr) * 32 + lg * 8);
      rls8[hh] = 0.125f / lsbuf[hh][qh + lr];
    }
    const u32* pkb2 = packed + (size_t)(b * 2048 + q0 + qh) * 64;
#pragma unroll 2
    for (int ch = c0; ch < c0 + 8; ch++) {
      uint2 mw = *(const uint2*)(pkb2 + lr * 64 + ch * 2);
#pragma unroll
      for (int j = 0; j < 4; j++) {
        f32x4 macc = {};
#pragma unroll
        for (int hh = 0; hh < 8; hh++) {
          const u16* kbh = kw + (size_t)((b * 8 + hh) * 2048) * 32;
          short8 kf = *(const short8*)(kbh +
              (size_t)(ch * 64 + j * 16 + lr) * 32 + lg * 8);
          f32x4 z = {};
          __builtin_amdgcn_s_setprio(1);
          f32x4 s = __builtin_amdgcn_mfma_f32_16x16x32_bf16(kf, qfh[hh], z, 0, 0, 0);
          __builtin_amdgcn_s_setprio(0);
#pragma unroll
          for (int rr = 0; rr < 4; rr++)
            macc[rr] = fmaf(__builtin_exp2f(s[rr]), rls8[hh], macc[rr]);
        }
        u32 wj = ((j & 2) ? mw.y : mw.x) >> ((j & 1) * 16 + lg * 4);
        f32x4 o;
#pragma unroll
        for (int rr = 0; rr < 4; rr++)
          o[rr] = ((wj >> rr) & 1u) ? macc[rr] : 0.0f;
        *(f32x4*)(out2 + (size_t)(b * 2048 + q0 + qh + lr) * 2048 +
                  ch * 64 + j * 16 + lg * 4) = o;
      }
    }
  }
}

// ---------------- out-proj + LayerNorm -> f32 ----------------
__global__ __launch_bounds__(256) void k_oproj(
    const u16* __restrict__ ao, const u16* __restrict__ wto,
    const float* __restrict__ bo, const float* __restrict__ gamma,
    const float* __restrict__ beta, float* __restrict__ out) {
  int l = threadIdx.x & 63, w = threadIdx.x >> 6;
  int lr = l & 15, lg = l >> 4;
  int row0 = blockIdx.x * 64 + w * 16;
  f32x4 acc[16] = {};
  const u16* ar = ao + (size_t)(row0 + lr) * 256 + lg * 8;
  const u16* wr = wto + lr * 256 + lg * 8;
  for (int k0 = 0; k0 < 256; k0 += 32) {
    short8 a = *(const short8*)(ar + k0);
#pragma unroll
    for (int ct = 0; ct < 16; ct++) {
      short8 bb = *(const short8*)(wr + ct * 16 * 256 + k0);
      acc[ct] = __builtin_amdgcn_mfma_f32_16x16x32_bf16(a, bb, acc[ct], 0, 0, 0);
    }
  }
  float sum[4] = {0, 0, 0, 0}, sq[4] = {0, 0, 0, 0};
#pragma unroll
  for (int ct = 0; ct < 16; ct++) {
    float bs = bo[ct * 16 + lr];
#pragma unroll
    for (int rr = 0; rr < 4; rr++) {
      float v = acc[ct][rr] + bs;
      acc[ct][rr] = v;
      sum[rr] += v; sq[rr] += v * v;
    }
  }
#pragma unroll
  for (int rr = 0; rr < 4; rr++) {
    float s = sum[rr], q = sq[rr];
    s += __shfl_xor(s, 1); s += __shfl_xor(s, 2);
    s += __shfl_xor(s, 4); s += __shfl_xor(s, 8);
    q += __shfl_xor(q, 1); q += __shfl_xor(q, 2);
    q += __shfl_xor(q, 4); q += __shfl_xor(q, 8);
    float mu = s * (1.0f / 256.0f);
    float var = fmaxf(q * (1.0f / 256.0f) - mu * mu, 0.0f);
    sum[rr] = mu;
    sq[rr] = rsqrtf(var + 1e-5f);
  }
#pragma unroll
  for (int ct = 0; ct < 16; ct++) {
    float g = gamma[ct * 16 + lr], be = beta[ct * 16 + lr];
#pragma unroll
    for (int rr = 0; rr < 4; rr++) {
      int n = row0 + lg * 4 + rr;
      out[(size_t)n * 256 + ct * 16 + lr] =
          ((acc[ct][rr] - sum[rr]) * sq[rr]) * g + be;
    }
  }
}

extern "C" void kernel_launch(void* const* d_in, const int* in_sizes, int n_in,
                              void* d_out, int out_size, void* d_ws, size_t ws_size,
                              hipStream_t stream) {
  const float* x    = (const float*)d_in[0];
  const int*   adj  = (const int*)d_in[1];
  const float* Wq   = (const float*)d_in[2];
  const float* bq   = (const float*)d_in[3];
  const float* Wk   = (const float*)d_in[4];
  const float* bk   = (const float*)d_in[5];
  const float* Wv   = (const float*)d_in[6];
  const float* bv   = (const float*)d_in[7];
  const float* Wo   = (const float*)d_in[8];
  const float* bo   = (const float*)d_in[9];
  const float* gamma= (const float*)d_in[10];
  const float* beta = (const float*)d_in[11];

  char* ws = (char*)d_ws;
  u16* wtq = (u16*)(ws + 0);
  u16* wtk = (u16*)(ws + 131072);
  u16* wtv = (u16*)(ws + 262144);
  u16* wto = (u16*)(ws + 393216);
  u16* qw  = (u16*)(ws + 524288);
  u16* kw  = (u16*)(ws + 8912896);
  u16* vt  = (u16*)(ws + 17301504);
  u16* ao  = (u16*)(ws + 25690112);
  u32* pk  = (u32*)(ws + 34078720);

  float* out  = (float*)d_out;
  float* out2 = out + (size_t)8 * 2048 * 256;

  k_prep<<<dim3(2304), dim3(256), 0, stream>>>(adj, pk, Wq, Wk, Wv, Wo,
                                               wtq, wtk, wtv, wto);
  k_qkv<<<dim3(12, 256), dim3(256), 0, stream>>>(x, wtq, bq, bk, bv, qw, kw, vt);
  k_attn<<<dim3(512), dim3(512), 0, stream>>>(qw, kw, vt, pk, ao, out2);
  k_oproj<<<dim3(256), dim3(256), 0, stream>>>(ao, wto, bo, gamma, beta, out);
}